// Round 5
// baseline (289.279 us; speedup 1.0000x reference)
//
#include <hip/hip_runtime.h>
#include <hip/hip_bf16.h>
#include <stdint.h>

#define TKS    4096   // tokens = 2*2048
#define KD     4096   // in_features
#define NSF    410    // split_f
#define NPARTS 10
#define NPAD   512    // padded Wfc rows
#define OUTF   4096

#define BM 64
#define BN 64
#define BK 128        // two 64-wide granule tiles per K iteration

typedef unsigned short u16;
typedef __attribute__((ext_vector_type(8))) short bf16x8;
typedef __attribute__((ext_vector_type(4))) float f32x4;

// ---- workspace layout (~4.4 MB) ----
#define WS_BSW 0                                     // u16[512*4096] swizzled bf16 Wfc
#define WS_G   ((size_t)NPAD * KD * 2)               // float[512*10]
#define WS_C   (WS_G + (size_t)NPAD * NPARTS * 4)    // float[512]
#define WS_SX  (WS_C + (size_t)NPAD * 4)             // float[4096*10]
#define WS_WT  (WS_SX + (size_t)TKS * NPARTS * 4)    // float[11*4096]

__device__ inline u16 f2bf(float f) {
    union { __hip_bfloat16 b; u16 u; } cv;
    cv.b = __float2bfloat16(f);
    return cv.u;
}

// granule index g in [0,512) -> (row, col) of a 64x64 tile.
// g = slot*64 + q*16 + ml ; slot = hi*4 + ks*2 + lo
// row = hi*32 + lo*16 + ml ; col = ks*32 + q*8
// MFMA read for (hi,lo,ks): addr = (slot*64 + lane)*16B -> conflict-free (proven R2-R4).
__device__ inline int g_row(int g) { int s = g >> 6; return (s >> 2) * 32 + (s & 1) * 16 + (g & 15); }
__device__ inline int g_col(int g) { int s = g >> 6; return ((s >> 1) & 1) * 32 + ((g >> 4) & 3) * 8; }

// ============ prep_a: WT[n][k] = Wexp[k][n]; WT[10][k] = bexp[k] =============
__global__ __launch_bounds__(256) void prep_a(const float* __restrict__ Wexp,
                                              const float* __restrict__ bexp,
                                              float* __restrict__ WT) {
    const int k = blockIdx.x * 256 + threadIdx.x;
#pragma unroll
    for (int n = 0; n < NPARTS; ++n) WT[(size_t)n * KD + k] = Wexp[(size_t)k * NPARTS + n];
    WT[(size_t)NPARTS * KD + k] = bexp[k];
}

// ============ retile_b: Wfc (f32) -> bsw (bf16 granule-tiled, rows>=410 zero)
// grid 7 rb x 64 kt
__global__ __launch_bounds__(256) void retile_b(const float* __restrict__ Wfc,
                                                u16* __restrict__ bsw) {
    const int kt = blockIdx.x & 63, rb = blockIdx.x >> 6;
    const int tid = threadIdx.x;
    u16* tout = bsw + ((size_t)(rb * 64 + kt) * 512) * 8;
#pragma unroll
    for (int j = 0; j < 2; ++j) {
        const int g = j * 256 + tid;
        const int r = rb * 64 + g_row(g);
        uint4 pk = make_uint4(0u, 0u, 0u, 0u);
        if (r < NSF) {
            const float* src = Wfc + (size_t)r * KD + kt * 64 + g_col(g);
            float4 v0 = *(const float4*)src;
            float4 v1 = *(const float4*)(src + 4);
            u16 h[8] = { f2bf(v0.x), f2bf(v0.y), f2bf(v0.z), f2bf(v0.w),
                         f2bf(v1.x), f2bf(v1.y), f2bf(v1.z), f2bf(v1.w) };
            pk = *(uint4*)h;
        }
        *(uint4*)&tout[(size_t)g * 8] = pk;
    }
}

// ============ prep_b: G[f][n] = Wfc[f]·WT[n]; c[f] = Wfc[f]·bexp + bfc[f] ====
// grid 410; all reads coalesced (WT rows are contiguous, L2-hot)
__global__ __launch_bounds__(256) void prep_b(const float* __restrict__ Wfc,
                                              const float* __restrict__ bfc,
                                              const float* __restrict__ WT,
                                              float* __restrict__ G,
                                              float* __restrict__ c) {
    const int f = blockIdx.x;
    const int tid = threadIdx.x;
    float acc[NPARTS + 1];
#pragma unroll
    for (int n = 0; n <= NPARTS; ++n) acc[n] = 0.f;

#pragma unroll
    for (int i = 0; i < 4; ++i) {
        const int k = i * 1024 + tid * 4;
        float4 wv = *(const float4*)&Wfc[(size_t)f * KD + k];
#pragma unroll
        for (int n = 0; n <= NPARTS; ++n) {
            float4 t = *(const float4*)&WT[(size_t)n * KD + k];
            acc[n] += wv.x * t.x + wv.y * t.y + wv.z * t.z + wv.w * t.w;
        }
    }
#pragma unroll
    for (int off = 32; off >= 1; off >>= 1)
#pragma unroll
        for (int n = 0; n <= NPARTS; ++n) acc[n] += __shfl_xor(acc[n], off);

    __shared__ float red[4][NPARTS + 1];
    const int w = tid >> 6, lane = tid & 63;
    if (lane == 0) {
#pragma unroll
        for (int n = 0; n <= NPARTS; ++n) red[w][n] = acc[n];
    }
    __syncthreads();
    if (tid < NPARTS)
        G[(size_t)f * NPARTS + tid] = red[0][tid] + red[1][tid] + red[2][tid] + red[3][tid];
    if (tid == NPARTS)
        c[f] = red[0][NPARTS] + red[1][NPARTS] + red[2][NPARTS] + red[3][NPARTS] + bfc[f];
}

// ============ sel: sx[t][n] = x[t]·Wsel[n] + bsel[n]  (f32 exact) ============
__global__ __launch_bounds__(256) void sel_kernel(const float* __restrict__ x,
                                                  const float* __restrict__ Wsel,
                                                  const float* __restrict__ bsel,
                                                  float* __restrict__ sx) {
    __shared__ float wsl[NPARTS][512];
    const int tid  = threadIdx.x;
    const int lane = tid & 63;
    const int w    = tid >> 6;
    const int t0   = blockIdx.x * 8 + w * 2;

    float acc0[NPARTS], acc1[NPARTS];
#pragma unroll
    for (int n = 0; n < NPARTS; ++n) { acc0[n] = 0.f; acc1[n] = 0.f; }

    const float* xr0 = x + (size_t)t0 * KD;
    const float* xr1 = xr0 + KD;

    for (int ch = 0; ch < 8; ++ch) {
        __syncthreads();
#pragma unroll
        for (int it = 0; it < 5; ++it) {
            int idx = it * 256 + tid;
            int n = idx >> 7, c4 = (idx & 127) * 4;
            *(float4*)&wsl[n][c4] = *(const float4*)&Wsel[n * KD + ch * 512 + c4];
        }
        __syncthreads();
#pragma unroll
        for (int j = 0; j < 2; ++j) {
            int kl = j * 256 + lane * 4;
            float4 x0 = *(const float4*)&xr0[ch * 512 + kl];
            float4 x1 = *(const float4*)&xr1[ch * 512 + kl];
#pragma unroll
            for (int n = 0; n < NPARTS; ++n) {
                float4 wv = *(float4*)&wsl[n][kl];
                acc0[n] += x0.x * wv.x + x0.y * wv.y + x0.z * wv.z + x0.w * wv.w;
                acc1[n] += x1.x * wv.x + x1.y * wv.y + x1.z * wv.z + x1.w * wv.w;
            }
        }
    }
#pragma unroll
    for (int off = 32; off >= 1; off >>= 1)
#pragma unroll
        for (int n = 0; n < NPARTS; ++n) {
            acc0[n] += __shfl_xor(acc0[n], off);
            acc1[n] += __shfl_xor(acc1[n], off);
        }
    if (lane == 0) {
#pragma unroll
        for (int n = 0; n < NPARTS; ++n) {
            float bs = bsel[n];
            sx[(size_t)t0 * NPARTS + n]       = acc0[n] + bs;
            sx[(size_t)(t0 + 1) * NPARTS + n] = acc1[n] + bs;
        }
    }
}

// ============ main: A = x·Wfc^T, m93-style VGPR pipeline ====================
// grid 448 = 7 fb x 64 tb; loads at top of iter (into VGPRs), ds_write at
// bottom -> barrier drains nothing; load latency hides under MFMA section.
__global__ __launch_bounds__(256, 2) void main_kernel(const float* __restrict__ x,
                                                      const u16*   __restrict__ bsw,
                                                      const float* __restrict__ G,
                                                      const float* __restrict__ cvec,
                                                      const float* __restrict__ sx,
                                                      float* __restrict__ out) {
    __shared__ __align__(16) u16 As[2][8192];   // 2 x 16 KB
    __shared__ __align__(16) u16 Bs[2][8192];   // 2 x 16 KB
    __shared__ float sxs[BM][NPARTS];
    __shared__ float Gs[BN][NPARTS];
    __shared__ float cs[BN];

    const int tid = threadIdx.x;
    const int fb  = blockIdx.x >> 6;    // 0..6
    const int tb  = blockIdx.x & 63;

    const int lane = tid & 63;
    const int w  = tid >> 6;
    const int wr = w >> 1, wc = w & 1;
    const int q  = lane >> 4, ml = lane & 15;

    f32x4 acc[2][2];
#pragma unroll
    for (int mi = 0; mi < 2; ++mi)
#pragma unroll
        for (int ni = 0; ni < 2; ++ni) acc[mi][ni] = (f32x4){0.f, 0.f, 0.f, 0.f};

    // per-thread staging geometry: 4 A-granules (f32 from x) + 4 B-granules
    const float* aptr[4];
    const u16*   bptr[4];
    int go[4];
#pragma unroll
    for (int j = 0; j < 4; ++j) {
        const int gg = j * 256 + tid;        // 0..1023 within BK=128 slab
        const int tile = gg >> 9;            // which 64-col granule tile
        const int gl   = gg & 511;
        aptr[j] = x + (size_t)(tb * 64 + g_row(gl)) * KD + tile * 64 + g_col(gl);
        bptr[j] = bsw + ((size_t)(fb * 64 + tile) * 512 + gl) * 8;
        go[j] = gg * 8;
    }

    // epilogue staging (visible after first barrier)
    for (int idx = tid; idx < BM * NPARTS; idx += 256)
        sxs[idx / NPARTS][idx % NPARTS] = sx[(size_t)(tb * BM + idx / NPARTS) * NPARTS + idx % NPARTS];
    for (int idx = tid; idx < BN * NPARTS; idx += 256)
        Gs[idx / NPARTS][idx % NPARTS] = G[(size_t)(fb * BN + idx / NPARTS) * NPARTS + idx % NPARTS];
    if (tid < BN) cs[tid] = cvec[fb * BN + tid];

    float4 a0[4], a1[4];
    uint4  bq[4];
    // prologue: stage iter 0
#pragma unroll
    for (int j = 0; j < 4; ++j) {
        a0[j] = *(const float4*)(aptr[j]);
        a1[j] = *(const float4*)(aptr[j] + 4);
        bq[j] = *(const uint4*)(bptr[j]);
    }
#pragma unroll
    for (int j = 0; j < 4; ++j) {
        u16 h[8] = { f2bf(a0[j].x), f2bf(a0[j].y), f2bf(a0[j].z), f2bf(a0[j].w),
                     f2bf(a1[j].x), f2bf(a1[j].y), f2bf(a1[j].z), f2bf(a1[j].w) };
        *(uint4*)&As[0][go[j]] = *(uint4*)h;
        *(uint4*)&Bs[0][go[j]] = bq[j];
    }
    __syncthreads();

    int buf = 0;
#pragma unroll 2
    for (int it = 0; it < KD / BK; ++it) {
        const bool pre = (it + 1) < KD / BK;
        if (pre) {   // issue next-slab loads FIRST; latency spans the MFMA section
            const int ko = (it + 1) * BK;
#pragma unroll
            for (int j = 0; j < 4; ++j) {
                a0[j] = *(const float4*)(aptr[j] + ko);
                a1[j] = *(const float4*)(aptr[j] + ko + 4);
                bq[j] = *(const uint4*)(bptr[j] + (size_t)(it + 1) * 8192);
            }
        }
#pragma unroll
        for (int ks = 0; ks < 4; ++ks) {
            const int tb2 = (ks >> 1) * 512;
            const int kl  = ks & 1;
            bf16x8 av[2], bv[2];
#pragma unroll
            for (int mi = 0; mi < 2; ++mi)
                av[mi] = *(const bf16x8*)&As[buf][(tb2 + ((wr * 2 + kl) * 2 + mi) * 64 + lane) * 8];
#pragma unroll
            for (int ni = 0; ni < 2; ++ni)
                bv[ni] = *(const bf16x8*)&Bs[buf][(tb2 + ((wc * 2 + kl) * 2 + ni) * 64 + lane) * 8];
#pragma unroll
            for (int mi = 0; mi < 2; ++mi)
#pragma unroll
                for (int ni = 0; ni < 2; ++ni)
                    acc[mi][ni] = __builtin_amdgcn_mfma_f32_16x16x32_bf16(
                        av[mi], bv[ni], acc[mi][ni], 0, 0, 0);
        }
        if (pre) {   // cvt waits on the loads issued one MFMA-section ago
#pragma unroll
            for (int j = 0; j < 4; ++j) {
                u16 h[8] = { f2bf(a0[j].x), f2bf(a0[j].y), f2bf(a0[j].z), f2bf(a0[j].w),
                             f2bf(a1[j].x), f2bf(a1[j].y), f2bf(a1[j].z), f2bf(a1[j].w) };
                *(uint4*)&As[buf ^ 1][go[j]] = *(uint4*)h;
                *(uint4*)&Bs[buf ^ 1][go[j]] = bq[j];
            }
        }
        __syncthreads();    // drains only lgkm (ds_writes); vmcnt already 0
        buf ^= 1;
    }

    // ---- epilogue: out[t, n*410+f] = A + sx[t][n]*G[f][n] + c[f] ----
#pragma unroll
    for (int ni = 0; ni < 2; ++ni) {
        const int fl = wc * 32 + ni * 16 + ml;
        const int fg = fb * BN + fl;
        if (fg >= NSF) continue;
        const float cv = cs[fl];
        float gv[NPARTS];
#pragma unroll
        for (int n = 0; n < NPARTS; ++n) gv[n] = Gs[fl][n];
#pragma unroll
        for (int mi = 0; mi < 2; ++mi) {
#pragma unroll
            for (int r = 0; r < 4; ++r) {
                const int tl = wr * 32 + mi * 16 + q * 4 + r;
                const float av = acc[mi][ni][r] + cv;
                float* orow = out + (size_t)(tb * BM + tl) * OUTF;
#pragma unroll
                for (int n = 0; n < NPARTS; ++n) {
                    int j = n * NSF + fg;
                    if (j < OUTF) orow[j] = av + sxs[tl][n] * gv[n];
                }
            }
        }
    }
}

extern "C" void kernel_launch(void* const* d_in, const int* in_sizes, int n_in,
                              void* d_out, int out_size, void* d_ws, size_t ws_size,
                              hipStream_t stream) {
    const float* x    = (const float*)d_in[0];
    const float* Wsel = (const float*)d_in[1];
    const float* bsel = (const float*)d_in[2];
    const float* Wexp = (const float*)d_in[3];
    const float* bexp = (const float*)d_in[4];
    const float* Wfc  = (const float*)d_in[5];
    const float* bfc  = (const float*)d_in[6];
    float* out = (float*)d_out;

    char* ws = (char*)d_ws;
    u16*   bsw  = (u16*)  (ws + WS_BSW);
    float* G    = (float*)(ws + WS_G);
    float* c    = (float*)(ws + WS_C);
    float* sx   = (float*)(ws + WS_SX);
    float* WT   = (float*)(ws + WS_WT);

    prep_a<<<dim3(16), dim3(256), 0, stream>>>(Wexp, bexp, WT);
    retile_b<<<dim3(7 * 64), dim3(256), 0, stream>>>(Wfc, bsw);
    prep_b<<<dim3(NSF), dim3(256), 0, stream>>>(Wfc, bfc, WT, G, c);
    sel_kernel<<<dim3(TKS / 8), dim3(256), 0, stream>>>(x, Wsel, bsel, sx);
    main_kernel<<<dim3(7 * 64), dim3(256), 0, stream>>>(x, bsw, G, c, sx, out);
}

// Round 6
// 202.133 us; speedup vs baseline: 1.4311x; 1.4311x over previous
//
#include <hip/hip_runtime.h>
#include <hip/hip_bf16.h>
#include <stdint.h>

#define TKS    4096   // tokens = 2*2048
#define KD     4096   // in_features
#define NSF    410    // split_f
#define NPARTS 10
#define OUTF   4096

#define BM 32
#define BN 64
#define BK 64

typedef unsigned short u16;
typedef __attribute__((ext_vector_type(8))) short bf16x8;
typedef __attribute__((ext_vector_type(4))) float f32x4;

// ---- workspace layout (~37.8 MB) ----
#define WS_XB  0                                     // u16[4096*4096]  granule bf16 x (32-row tiles)
#define WS_BSW ((size_t)TKS * KD * 2)                // u16[512*4096]   granule bf16 Wfc (64-row tiles)
#define WS_WSL (WS_BSW + (size_t)512 * KD * 2)       // u16[16*4096]    granule bf16 Wsel
#define WS_WEX (WS_WSL + (size_t)16 * KD * 2)        // u16[16*4096]    granule bf16 Wexp^T (+bexp row 10)

__device__ inline u16 f2bf(float f) {
    union { __hip_bfloat16 b; u16 u; } cv;
    cv.b = __float2bfloat16(f);
    return cv.u;
}

typedef __attribute__((address_space(3))) unsigned int as3_uint;
typedef __attribute__((address_space(1))) unsigned int as1_uint;
__device__ inline void gl_lds16(const void* g, void* l) {
    __builtin_amdgcn_global_load_lds((as1_uint*)(uintptr_t)g,
                                     (as3_uint*)(uintptr_t)l, 16, 0, 0);
}

// 64-row tile granule g in [0,512): slot=g>>6 = hi*4+ks*2+lo
// row = hi*32+lo*16+(g&15) ; col = ks*32+((g>>4)&3)*8   (conflict-free, proven R2-R5)
__device__ inline int g_row(int g) { int s = g >> 6; return (s >> 2) * 32 + (s & 1) * 16 + (g & 15); }
__device__ inline int g_col(int g) { int s = g >> 6; return ((s >> 1) & 1) * 32 + ((g >> 4) & 3) * 8; }

// ============ prep_w: Wsel/Wexp -> 16-row granule-tiled bf16 =================
// wselb row ml (<10) = Wsel[ml]; wexpb row ml (<10) = Wexp[:,ml], row 10 = bexp.
// 16-row tile granule g in [0,128): row=(g&15), col=(g>>6)*32+((g>>4)&3)*8
__global__ __launch_bounds__(256) void prep_w(const float* __restrict__ Wsel,
                                              const float* __restrict__ Wexp,
                                              const float* __restrict__ bexp,
                                              u16* __restrict__ wselb,
                                              u16* __restrict__ wexpb) {
    const int kt = blockIdx.x;           // 0..63
    const int tid = threadIdx.x;
    const int g  = tid & 127;
    const int ml = g & 15;
    const int col = kt * 64 + (g >> 6) * 32 + ((g >> 4) & 3) * 8;
    u16 h[8];
    if (tid < 128) {
#pragma unroll
        for (int j = 0; j < 8; ++j)
            h[j] = (ml < NPARTS) ? f2bf(Wsel[(size_t)ml * KD + col + j]) : (u16)0;
        *(uint4*)&wselb[((size_t)kt * 128 + g) * 8] = *(uint4*)h;
    } else {
#pragma unroll
        for (int j = 0; j < 8; ++j)
            h[j] = (ml < NPARTS) ? f2bf(Wexp[(size_t)(col + j) * NPARTS + ml])
                 : (ml == NPARTS ? f2bf(bexp[col + j]) : (u16)0);
        *(uint4*)&wexpb[((size_t)kt * 128 + g) * 8] = *(uint4*)h;
    }
}

// ============ retile_b: Wfc (f32) -> bsw (bf16 granule-tiled, rows>=410 zero)
// grid 7 rb x 64 kt (proven R3)
__global__ __launch_bounds__(256) void retile_b(const float* __restrict__ Wfc,
                                                u16* __restrict__ bsw) {
    const int kt = blockIdx.x & 63, rb = blockIdx.x >> 6;
    const int tid = threadIdx.x;
    u16* tout = bsw + ((size_t)(rb * 64 + kt) * 512) * 8;
#pragma unroll
    for (int j = 0; j < 2; ++j) {
        const int g = j * 256 + tid;
        const int r = rb * 64 + g_row(g);
        uint4 pk = make_uint4(0u, 0u, 0u, 0u);
        if (r < NSF) {
            const float* src = Wfc + (size_t)r * KD + kt * 64 + g_col(g);
            float4 v0 = *(const float4*)src;
            float4 v1 = *(const float4*)(src + 4);
            u16 h[8] = { f2bf(v0.x), f2bf(v0.y), f2bf(v0.z), f2bf(v0.w),
                         f2bf(v1.x), f2bf(v1.y), f2bf(v1.z), f2bf(v1.w) };
            pk = *(uint4*)h;
        }
        *(uint4*)&tout[(size_t)g * 8] = pk;
    }
}

// ============ retile_x: x (f32) -> xb (bf16, 32-row granule tiles) ===========
// grid 128 tb x 64 kt; writes linear; reads 16-row groups (8192 blocks hide it)
__global__ __launch_bounds__(256) void retile_x(const float* __restrict__ x,
                                                u16* __restrict__ xb) {
    const int kt = blockIdx.x & 63, tb = blockIdx.x >> 6;   // tb 0..127
    const int g = threadIdx.x;                              // granule 0..255
    const int slot = g >> 6;                                // ks*2+lo
    const int row = (slot & 1) * 16 + (g & 15);
    const int col = (slot >> 1) * 32 + ((g >> 4) & 3) * 8;
    const float* src = x + (size_t)(tb * 32 + row) * KD + kt * 64 + col;
    float4 v0 = *(const float4*)src;
    float4 v1 = *(const float4*)(src + 4);
    u16 h[8] = { f2bf(v0.x), f2bf(v0.y), f2bf(v0.z), f2bf(v0.w),
                 f2bf(v1.x), f2bf(v1.y), f2bf(v1.z), f2bf(v1.w) };
    *(uint4*)&xb[((size_t)(tb * 64 + kt) * 256 + g) * 8] = *(uint4*)h;
}

// ============ main: A = x·Wfc^T + in-loop sx/G/c via MFMA side-accs ==========
// grid 896 = 7 fb x 128 tb (fb-major for B L2 reuse); 4 waves:
// mt = w&1 (16-row m-tile), wc = w>>1 (32-col half). ~4 blocks/CU.
__global__ __launch_bounds__(256, 4) void main_kernel(const u16* __restrict__ xb,
                                                      const u16* __restrict__ bsw,
                                                      const u16* __restrict__ wselb,
                                                      const u16* __restrict__ wexpb,
                                                      const float* __restrict__ bsel,
                                                      const float* __restrict__ bfc,
                                                      float* __restrict__ out) {
    __shared__ __align__(16) u16 As[2][2048];   // 2 x 4 KB
    __shared__ __align__(16) u16 Bs[2][4096];   // 2 x 8 KB
    __shared__ __align__(16) u16 Wl[2][1024];   // 2 x 2 KB (Wsel slab)
    __shared__ __align__(16) u16 We[2][1024];   // 2 x 2 KB (Wexp^T slab)
    __shared__ float sxs[BM][NPARTS];
    __shared__ float Gs[BN][NPARTS];
    __shared__ float cs[BN];

    const int tid = threadIdx.x;
    const int fb  = blockIdx.x >> 7;    // 0..6
    const int tb  = blockIdx.x & 127;   // 0..127

    const int lane = tid & 63;
    const int w  = tid >> 6;
    const int mt = w & 1, wc = w >> 1;
    const int q  = lane >> 4, ml = lane & 15;

    f32x4 acc[2]   = { (f32x4){0.f,0.f,0.f,0.f}, (f32x4){0.f,0.f,0.f,0.f} };
    f32x4 accsx    = (f32x4){0.f,0.f,0.f,0.f};
    f32x4 accG[2]  = { (f32x4){0.f,0.f,0.f,0.f}, (f32x4){0.f,0.f,0.f,0.f} };

    const u16* ab = xb  + (size_t)tb * 131072;   // 64 slabs x 256 granules x 8
    const u16* bb = bsw + (size_t)fb * 262144;   // 64 slabs x 512 granules x 8

    // prologue: stage slab 0
    gl_lds16(ab + tid * 8, &As[0][tid * 8]);
    gl_lds16(bb + tid * 8, &Bs[0][tid * 8]);
    gl_lds16(bb + (256 + tid) * 8, &Bs[0][(256 + tid) * 8]);
    if (tid < 128) gl_lds16(wselb + tid * 8, &Wl[0][tid * 8]);
    else           gl_lds16(wexpb + (tid - 128) * 8, &We[0][(tid - 128) * 8]);
    __syncthreads();

    int buf = 0;
#pragma unroll 2
    for (int it = 0; it < KD / BK; ++it) {
        if (it + 1 < KD / BK) {
            const size_t ao = (size_t)(it + 1) * 2048;
            const size_t bo = (size_t)(it + 1) * 4096;
            const size_t wo = (size_t)(it + 1) * 1024;
            gl_lds16(ab + ao + tid * 8, &As[buf ^ 1][tid * 8]);
            gl_lds16(bb + bo + tid * 8, &Bs[buf ^ 1][tid * 8]);
            gl_lds16(bb + bo + (256 + tid) * 8, &Bs[buf ^ 1][(256 + tid) * 8]);
            if (tid < 128) gl_lds16(wselb + wo + tid * 8, &Wl[buf ^ 1][tid * 8]);
            else           gl_lds16(wexpb + wo + (tid - 128) * 8, &We[buf ^ 1][(tid - 128) * 8]);
        }
#pragma unroll
        for (int ks = 0; ks < 2; ++ks) {
            bf16x8 av  = *(const bf16x8*)&As[buf][((ks * 2 + mt) * 64 + lane) * 8];
            bf16x8 bv0 = *(const bf16x8*)&Bs[buf][((wc * 4 + ks * 2 + 0) * 64 + lane) * 8];
            bf16x8 bv1 = *(const bf16x8*)&Bs[buf][((wc * 4 + ks * 2 + 1) * 64 + lane) * 8];
            acc[0] = __builtin_amdgcn_mfma_f32_16x16x32_bf16(av, bv0, acc[0], 0, 0, 0);
            acc[1] = __builtin_amdgcn_mfma_f32_16x16x32_bf16(av, bv1, acc[1], 0, 0, 0);
            if (wc == 0) {   // sx for this wave's 16 token rows
                bf16x8 wf = *(const bf16x8*)&Wl[buf][(ks * 64 + lane) * 8];
                accsx = __builtin_amdgcn_mfma_f32_16x16x32_bf16(av, wf, accsx, 0, 0, 0);
            }
            if (mt == 0) {   // G/c for this wave's 32 f-rows
                bf16x8 ef = *(const bf16x8*)&We[buf][(ks * 64 + lane) * 8];
                accG[0] = __builtin_amdgcn_mfma_f32_16x16x32_bf16(bv0, ef, accG[0], 0, 0, 0);
                accG[1] = __builtin_amdgcn_mfma_f32_16x16x32_bf16(bv1, ef, accG[1], 0, 0, 0);
            }
        }
        __syncthreads();
        buf ^= 1;
    }

    // ---- post-loop: publish sx/G/c to LDS tables ----
    if (wc == 0 && ml < NPARTS) {
        const float bs = bsel[ml];
#pragma unroll
        for (int r = 0; r < 4; ++r)
            sxs[mt * 16 + q * 4 + r][ml] = accsx[r] + bs;
    }
    if (mt == 0) {
#pragma unroll
        for (int ni = 0; ni < 2; ++ni) {
#pragma unroll
            for (int r = 0; r < 4; ++r) {
                const int f = wc * 32 + ni * 16 + q * 4 + r;
                if (ml < NPARTS) Gs[f][ml] = accG[ni][r];
                else if (ml == NPARTS) {
                    const int fg = fb * BN + f;
                    cs[f] = accG[ni][r] + (fg < NSF ? bfc[fg] : 0.f);
                }
            }
        }
    }
    __syncthreads();

    // ---- epilogue: out[t, n*410+f] = A + sx[t][n]*G[f][n] + c[f] ----
#pragma unroll
    for (int ni = 0; ni < 2; ++ni) {
        const int fl = wc * 32 + ni * 16 + ml;
        const int fg = fb * BN + fl;
        if (fg >= NSF) continue;
        const float cv = cs[fl];
        float gv[NPARTS];
#pragma unroll
        for (int n = 0; n < NPARTS; ++n) gv[n] = Gs[fl][n];
#pragma unroll
        for (int r = 0; r < 4; ++r) {
            const int tl = mt * 16 + q * 4 + r;
            const float av = acc[ni][r] + cv;
            float* orow = out + (size_t)(tb * BM + tl) * OUTF;
#pragma unroll
            for (int n = 0; n < NPARTS; ++n) {
                int j = n * NSF + fg;
                if (j < OUTF) orow[j] = av + sxs[tl][n] * gv[n];
            }
        }
    }
}

extern "C" void kernel_launch(void* const* d_in, const int* in_sizes, int n_in,
                              void* d_out, int out_size, void* d_ws, size_t ws_size,
                              hipStream_t stream) {
    const float* x    = (const float*)d_in[0];
    const float* Wsel = (const float*)d_in[1];
    const float* bsel = (const float*)d_in[2];
    const float* Wexp = (const float*)d_in[3];
    const float* bexp = (const float*)d_in[4];
    const float* Wfc  = (const float*)d_in[5];
    const float* bfc  = (const float*)d_in[6];
    float* out = (float*)d_out;

    char* ws = (char*)d_ws;
    u16* xb    = (u16*)(ws + WS_XB);
    u16* bsw   = (u16*)(ws + WS_BSW);
    u16* wselb = (u16*)(ws + WS_WSL);
    u16* wexpb = (u16*)(ws + WS_WEX);

    prep_w<<<dim3(64), dim3(256), 0, stream>>>(Wsel, Wexp, bexp, wselb, wexpb);
    retile_b<<<dim3(7 * 64), dim3(256), 0, stream>>>(Wfc, bsw);
    retile_x<<<dim3(128 * 64), dim3(256), 0, stream>>>(x, xb);
    main_kernel<<<dim3(7 * 128), dim3(256), 0, stream>>>(xb, bsw, wselb, wexpb,
                                                         bsel, bfc, out);
}